// Round 6
// baseline (715.655 us; speedup 1.0000x reference)
//
#include <hip/hip_runtime.h>

#define NN 4096
#define EE 32768
#define ETOT (EE + NN)
#define HH 8
#define KK 4
#define MM 500
#define GG 2000
#define D0 256
#define C1 448
#define NEGS 0.2f
#define LNEPS 1e-5f

typedef unsigned short ushort;
typedef _Float16 half_t;
typedef __attribute__((ext_vector_type(8))) _Float16 half8;
typedef __attribute__((ext_vector_type(4))) float floatx4;

// ---------- helpers ----------

__device__ __forceinline__ void get_edge(const int* __restrict__ ei, int e, int& s, int& d) {
    if (e < EE) { s = ei[e]; d = ei[EE + e]; }
    else        { s = e - EE; d = e - EE; }   // self-loops appended
}

__device__ __forceinline__ half_t f2h(float x) { return (half_t)x; }  // RNE

__device__ __forceinline__ float lrelu(float v) { return (v >= 0.f) ? v : NEGS * v; }

// async global->LDS, 16 bytes/lane; LDS dest = wave-uniform base + lane*16
__device__ __forceinline__ void async_lds16(const half_t* g, half_t* l) {
    __builtin_amdgcn_global_load_lds(
        (const __attribute__((address_space(1))) unsigned int*)(const void*)g,
        (__attribute__((address_space(3))) unsigned int*)(void*)l,
        16, 0, 0);
}

// ---------- CSR build ----------

__global__ void k_zero_i(int* p, int n) {
    int i = blockIdx.x * 256 + threadIdx.x;
    if (i < n) p[i] = 0;
}

__global__ void k_zero_f(float* p, int n) {
    int i = blockIdx.x * 256 + threadIdx.x;
    if (i < n) p[i] = 0.f;
}

__global__ void k_count(const int* __restrict__ ei, int* deg) {
    int e = blockIdx.x * 256 + threadIdx.x;
    if (e < ETOT) { int s, d; get_edge(ei, e, s, d); atomicAdd(&deg[d], 1); }
}

__global__ void k_scan(const int* __restrict__ deg, int* rs, int n) {
    __shared__ int sums[1024];
    int tid = threadIdx.x;
    int base = tid * 4;
    int loc[4]; int s = 0;
    #pragma unroll
    for (int i = 0; i < 4; i++) {
        int v = (base + i < n) ? deg[base + i] : 0;
        loc[i] = s; s += v;
    }
    sums[tid] = s;
    __syncthreads();
    for (int off = 1; off < 1024; off <<= 1) {
        int v = (tid >= off) ? sums[tid - off] : 0;
        __syncthreads();
        sums[tid] += v;
        __syncthreads();
    }
    int prev = (tid > 0) ? sums[tid - 1] : 0;
    #pragma unroll
    for (int i = 0; i < 4; i++)
        if (base + i < n) rs[base + i] = prev + loc[i];
    if (tid == 1023) rs[n] = sums[1023];
}

__global__ void k_fill(const int* __restrict__ ei, const int* __restrict__ rs,
                       int* cur, int* csr_src) {
    int e = blockIdx.x * 256 + threadIdx.x;
    if (e < ETOT) {
        int s, d; get_edge(ei, e, s, d);
        int pos = rs[d] + atomicAdd(&cur[d], 1);
        csr_src[pos] = s;
    }
}

// ---------- fp32 -> fp16 elementwise (for x) ----------

__global__ void k_f2h(const float* __restrict__ in, half_t* __restrict__ out, int n) {
    int i = blockIdx.x * 256 + threadIdx.x;
    if (i < n) out[i] = f2h(in[i]);
}

// ---------- weight transpose + fp16: W[K][ldw] fp32 -> Wt[Npad][K] fp16 ----------

__global__ __launch_bounds__(256) void k_wt(const float* __restrict__ W,
                                            half_t* __restrict__ Wt,
                                            int Kd, int Nvalid, int ldw,
                                            long long sW, long long sWt) {
    __shared__ float t[32][33];
    const float* Wp = W + (size_t)blockIdx.z * sW;
    half_t* Wtp = Wt + (size_t)blockIdx.z * sWt;
    int n0 = blockIdx.x * 32, k0 = blockIdx.y * 32;
    int tx = threadIdx.x & 31, ty = threadIdx.x >> 5;   // ty 0..7
    #pragma unroll
    for (int i = 0; i < 32; i += 8)
        t[ty + i][tx] = (n0 + tx < Nvalid) ? Wp[(size_t)(k0 + ty + i) * ldw + n0 + tx] : 0.f;
    __syncthreads();
    #pragma unroll
    for (int i = 0; i < 32; i += 8)
        Wtp[(size_t)(n0 + ty + i) * Kd + k0 + tx] = f2h(t[tx][ty + i]);
}

// ---------- layer-1 precompute: Wa[k][h] = sum_c W1[k][h*C1+c] * a[h][c] ----------

__global__ void k_wa(const float* __restrict__ W, const float* __restrict__ as_,
                     const float* __restrict__ ad_, float* was, float* wad) {
    int b = blockIdx.x;                 // 0..2047
    int k = b & (D0 - 1), h = b >> 8;
    int lane = threadIdx.x;
    const float* row = W + (size_t)k * (HH * C1) + (size_t)h * C1;
    float ss = 0.f, dd = 0.f;
    for (int c = lane; c < C1; c += 64) {
        float w = row[c];
        ss += w * as_[h * C1 + c];
        dd += w * ad_[h * C1 + c];
    }
    #pragma unroll
    for (int o = 32; o > 0; o >>= 1) {
        ss += __shfl_down(ss, o, 64);
        dd += __shfl_down(dd, o, 64);
    }
    if (lane == 0) { was[k * HH + h] = ss; wad[k * HH + h] = dd; }
}

// ---------- layer-1 attention dots from raw x: s[n,h] = x[n]·Wa[:,h] ----------

__global__ void k_sd_pre(const float* __restrict__ x, const float* __restrict__ was,
                         const float* __restrict__ wad, float* s, float* d) {
    int n = blockIdx.x / HH, h = blockIdx.x % HH;
    int lane = threadIdx.x;
    float ss = 0.f, dd = 0.f;
    for (int k = lane; k < D0; k += 64) {
        float xv = x[(size_t)n * D0 + k];
        ss += xv * was[k * HH + h];
        dd += xv * wad[k * HH + h];
    }
    #pragma unroll
    for (int o = 32; o > 0; o >>= 1) {
        ss += __shfl_down(ss, o, 64);
        dd += __shfl_down(dd, o, 64);
    }
    if (lane == 0) { s[n * HH + h] = ss; d[n * HH + h] = dd; }
}

// ---------- layer-1 aggregation of x (fp16), fused softmax, per head ----------
// agg1[n][h][D0] = sum_e exp(leaky(s[src]+d[n]))/z * x16[src]

__global__ __launch_bounds__(256) void k_agg1(
    const half_t* __restrict__ x16, const float* __restrict__ s, const float* __restrict__ d,
    const int* __restrict__ csr_src, const int* __restrict__ rs,
    half_t* __restrict__ agg1) {
    __shared__ int sh_src[256];
    __shared__ float sh_p[256 * HH];
    __shared__ float dloc[HH];
    __shared__ float zsh[256];
    __shared__ float zfin[HH];
    int n = blockIdx.x, tid = threadIdx.x;
    int h = tid >> 5, t = tid & 31;      // head, chunk (D0/8 = 32 chunks)
    int start = rs[n], end = rs[n + 1];
    if (tid < HH) dloc[tid] = d[n * HH + tid];
    float zloc = 0.f;
    int hp = tid & (HH - 1);             // head for p-compute entries
    float acc[8];
    #pragma unroll
    for (int q = 0; q < 8; q++) acc[q] = 0.f;

    for (int e0 = start; e0 < end; e0 += 256) {
        int cnt = min(256, end - e0);
        if (tid < cnt) sh_src[tid] = csr_src[e0 + tid];
        __syncthreads();
        for (int j = tid; j < cnt * HH; j += 256) {
            int i = j >> 3;
            float p = __expf(lrelu(s[sh_src[i] * HH + hp] + dloc[hp]));
            sh_p[j] = p; zloc += p;
        }
        __syncthreads();
        for (int i = 0; i < cnt; i++) {
            float p = sh_p[i * HH + h];
            half8 v = *(const half8*)(x16 + (size_t)sh_src[i] * D0 + t * 8);
            #pragma unroll
            for (int q = 0; q < 8; q++) acc[q] += p * (float)v[q];
        }
        __syncthreads();
    }
    zsh[tid] = zloc;
    __syncthreads();
    if (tid < HH) {
        float zt = 0.f;
        for (int i = tid; i < 256; i += HH) zt += zsh[i];
        zfin[tid] = 1.f / (zt + 1e-16f);
    }
    __syncthreads();
    float zi = zfin[h];
    half8 o;
    #pragma unroll
    for (int q = 0; q < 8; q++) o[q] = f2h(acc[q] * zi);
    *(half8*)(agg1 + (size_t)n * (HH * D0) + h * D0 + t * 8) = o;
}

// ---------- bias + ReLU + LayerNorm: xp16 row -> Ah fp16 (layer 1 tail) ----------

__global__ __launch_bounds__(256) void k_bln(
    const half_t* __restrict__ xp, const float* __restrict__ bias,
    const float* __restrict__ gam, const float* __restrict__ bet,
    half_t* __restrict__ outh, int Dout) {
    __shared__ float red[256];
    __shared__ float red2[256];
    int n = blockIdx.x, tid = threadIdx.x;
    int NCH = Dout >> 3;
    float vals[2][8];
    float sum = 0.f, sumsq = 0.f;
    int ai = 0;
    for (int ch = tid; ch < NCH; ch += 256, ai++) {
        half8 v = *(const half8*)(xp + (size_t)n * Dout + (ch << 3));
        #pragma unroll
        for (int q = 0; q < 8; q++) {
            float f = fmaxf((float)v[q] + bias[(ch << 3) + q], 0.f);
            vals[ai][q] = f;
            sum += f; sumsq += f * f;
        }
    }
    red[tid] = sum; red2[tid] = sumsq;
    __syncthreads();
    for (int o = 128; o > 0; o >>= 1) {
        if (tid < o) { red[tid] += red[tid + o]; red2[tid] += red2[tid + o]; }
        __syncthreads();
    }
    float mu = red[0] / Dout;
    float var = red2[0] / Dout - mu * mu;
    float rstd = rsqrtf(var + LNEPS);
    ai = 0;
    for (int ch = tid; ch < NCH; ch += 256, ai++) {
        half8 o;
        #pragma unroll
        for (int q = 0; q < 8; q++)
            o[q] = f2h((vals[ai][q] - mu) * rstd * gam[(ch << 3) + q] + bet[(ch << 3) + q]);
        *(half8*)(outh + (size_t)n * Dout + (ch << 3)) = o;
    }
}

// ---------- fp16 MFMA GEMM: C[M][ldc] = A[M][Kd] * Bt[.][Kd]^T, fp16 out ----------
// 128x128 tile, BK=64, XOR-swizzled LDS (conflict-free, global_load_lds-compatible)

#define BM 128
#define BN 128
#define BK 64

__global__ __launch_bounds__(256) void k_gemm_mfma(
    const half_t* __restrict__ A, const half_t* __restrict__ Bt,
    half_t* __restrict__ C,
    int Kd, int lda, int Nreal, int ldc,
    long long strideA, long long strideBt, long long strideC)
{
    __shared__ __align__(16) half_t As[BM * BK];
    __shared__ __align__(16) half_t Bs[BN * BK];

    const half_t* Ap  = A  + (size_t)blockIdx.z * strideA;
    const half_t* Btp = Bt + (size_t)blockIdx.z * strideBt;
    half_t* Cp = C + (size_t)blockIdx.z * strideC;
    int col0 = blockIdx.x * BN, row0 = blockIdx.y * BM;

    int lane = threadIdx.x & 63;
    int wave = threadIdx.x >> 6;
    int wm = (wave >> 1) * 64, wn = (wave & 1) * 64;

    int srow = wave * 32 + (lane >> 3);
    int gchunk = (lane & 7) ^ ((lane >> 3) & 7);
    const half_t* ga = Ap  + (size_t)(row0 + srow) * lda + gchunk * 8;
    const half_t* gb = Btp + (size_t)(col0 + srow) * Kd + gchunk * 8;
    half_t* lA = &As[(wave * 32) * BK];
    half_t* lB = &Bs[(wave * 32) * BK];

    int r = lane & 15;
    int rx = r & 7;

    floatx4 acc[4][4];
    #pragma unroll
    for (int i = 0; i < 4; i++)
        #pragma unroll
        for (int j = 0; j < 4; j++) acc[i][j] = (floatx4){0.f, 0.f, 0.f, 0.f};

    for (int k0 = 0; k0 < Kd; k0 += BK) {
        #pragma unroll
        for (int j = 0; j < 4; j++) {
            async_lds16(ga + k0 + (size_t)(j * 8) * lda, lA + (j * 8) * BK);
            async_lds16(gb + k0 + (size_t)(j * 8) * Kd, lB + (j * 8) * BK);
        }
        __syncthreads();
        #pragma unroll
        for (int kk = 0; kk < BK; kk += 32) {
            int phys = (((kk >> 3) + (lane >> 4)) ^ rx) << 3;
            half8 a[4], b[4];
            #pragma unroll
            for (int i = 0; i < 4; i++)
                a[i] = *(const half8*)&As[(wm + i * 16 + r) * BK + phys];
            #pragma unroll
            for (int j = 0; j < 4; j++)
                b[j] = *(const half8*)&Bs[(wn + j * 16 + r) * BK + phys];
            #pragma unroll
            for (int i = 0; i < 4; i++)
                #pragma unroll
                for (int j = 0; j < 4; j++)
                    acc[i][j] = __builtin_amdgcn_mfma_f32_16x16x32_f16(a[i], b[j], acc[i][j], 0, 0, 0);
        }
        __syncthreads();
    }

    int q4 = (lane >> 4) * 4;
    #pragma unroll
    for (int i = 0; i < 4; i++) {
        #pragma unroll
        for (int rr = 0; rr < 4; rr++) {
            int row = row0 + wm + i * 16 + q4 + rr;
            #pragma unroll
            for (int j = 0; j < 4; j++) {
                int col = col0 + wn + j * 16 + (lane & 15);
                if (col < Nreal) Cp[(size_t)row * ldc + col] = f2h(acc[i][j][rr]);
            }
        }
    }
}

// ---------- per-(node,head) attention dots (fp16 xp) ----------

__global__ void k_sd(const half_t* __restrict__ xp, const float* __restrict__ as_,
                     const float* __restrict__ ad_, float* s, float* d, int H, int C) {
    int n = blockIdx.x / H, h = blockIdx.x % H;
    int lane = threadIdx.x;
    const half_t* row = xp + (size_t)n * H * C + (size_t)h * C;
    const float* av = as_ + (size_t)h * C;
    const float* bv = ad_ + (size_t)h * C;
    float ss = 0.f, dd = 0.f;
    for (int c = lane; c < C; c += 64) {
        float x = (float)row[c];
        ss += x * av[c];
        dd += x * bv[c];
    }
    #pragma unroll
    for (int o = 32; o > 0; o >>= 1) {
        ss += __shfl_down(ss, o, 64);
        dd += __shfl_down(dd, o, 64);
    }
    if (lane == 0) { s[n * H + h] = ss; d[n * H + h] = dd; }
}

// ---------- aggregation + fused softmax + ReLU + LayerNorm; fp16 in/out ----------

__global__ __launch_bounds__(256) void k_agg_ln(
    const half_t* __restrict__ xp, const float* __restrict__ s, const float* __restrict__ d,
    const int* __restrict__ csr_src, const int* __restrict__ rs,
    const float* __restrict__ bias, const float* __restrict__ gam, const float* __restrict__ bet,
    half_t* __restrict__ outh, int C) {
    __shared__ int sh_src[256];
    __shared__ float sh_p[256 * HH];
    __shared__ float dloc[HH];
    __shared__ float zsh[256];
    __shared__ float zfin[HH];
    __shared__ float red[256];
    __shared__ float red2[256];
    int n = blockIdx.x, tid = threadIdx.x;
    int Dout = HH * C;
    int NCH = Dout >> 3;
    int CCH = C >> 3;
    int start = rs[n], end = rs[n + 1];
    if (tid < HH) dloc[tid] = d[n * HH + tid];
    float zloc = 0.f;
    int hp = tid & (HH - 1);
    float acc[2][8];
    #pragma unroll
    for (int a = 0; a < 2; a++)
        #pragma unroll
        for (int q = 0; q < 8; q++) acc[a][q] = 0.f;

    for (int e0 = start; e0 < end; e0 += 256) {
        int cnt = min(256, end - e0);
        if (tid < cnt) sh_src[tid] = csr_src[e0 + tid];
        __syncthreads();
        for (int j = tid; j < cnt * HH; j += 256) {
            int i = j >> 3;
            float p = __expf(lrelu(s[sh_src[i] * HH + hp] + dloc[hp]));
            sh_p[j] = p; zloc += p;
        }
        __syncthreads();
        int ai = 0;
        for (int ch = tid; ch < NCH; ch += 256, ai++) {
            int h = ch / CCH;
            float a0 = acc[ai][0], a1 = acc[ai][1], a2 = acc[ai][2], a3 = acc[ai][3];
            float a4 = acc[ai][4], a5 = acc[ai][5], a6 = acc[ai][6], a7 = acc[ai][7];
            for (int i = 0; i < cnt; i++) {
                float w = sh_p[i * HH + h];
                half8 v = *(const half8*)(xp + (size_t)sh_src[i] * Dout + (ch << 3));
                a0 += w * (float)v[0]; a1 += w * (float)v[1];
                a2 += w * (float)v[2]; a3 += w * (float)v[3];
                a4 += w * (float)v[4]; a5 += w * (float)v[5];
                a6 += w * (float)v[6]; a7 += w * (float)v[7];
            }
            acc[ai][0] = a0; acc[ai][1] = a1; acc[ai][2] = a2; acc[ai][3] = a3;
            acc[ai][4] = a4; acc[ai][5] = a5; acc[ai][6] = a6; acc[ai][7] = a7;
        }
        __syncthreads();
    }

    zsh[tid] = zloc;
    __syncthreads();
    if (tid < HH) {
        float zt = 0.f;
        for (int i = tid; i < 256; i += HH) zt += zsh[i];
        zfin[tid] = 1.f / (zt + 1e-16f);
    }
    __syncthreads();

    float vals[2][8];
    float sum = 0.f, sumsq = 0.f;
    int ai = 0;
    for (int ch = tid; ch < NCH; ch += 256, ai++) {
        float zi = zfin[ch / CCH];
        #pragma unroll
        for (int q = 0; q < 8; q++) {
            float v = acc[ai][q] * zi + bias[(ch << 3) + q];
            v = fmaxf(v, 0.f);
            vals[ai][q] = v;
            sum += v; sumsq += v * v;
        }
    }
    red[tid] = sum; red2[tid] = sumsq;
    __syncthreads();
    for (int o = 128; o > 0; o >>= 1) {
        if (tid < o) { red[tid] += red[tid + o]; red2[tid] += red2[tid + o]; }
        __syncthreads();
    }
    float mu = red[0] / Dout;
    float var = red2[0] / Dout - mu * mu;
    float rstd = rsqrtf(var + LNEPS);
    ai = 0;
    for (int ch = tid; ch < NCH; ch += 256, ai++) {
        half8 o;
        #pragma unroll
        for (int q = 0; q < 8; q++)
            o[q] = f2h((vals[ai][q] - mu) * rstd * gam[(ch << 3) + q] + bet[(ch << 3) + q]);
        *(half8*)(outh + (size_t)n * Dout + (ch << 3)) = o;
    }
}

// ---------- head aggregation + fused softmax: per_head + idx-scattered full ----------

__global__ __launch_bounds__(256) void k_agg_head(
    const half_t* __restrict__ xp, const float* __restrict__ s, const float* __restrict__ d,
    const int* __restrict__ csr_src, const int* __restrict__ rs,
    const float* __restrict__ bias, const int* __restrict__ idxm,
    float* out_full, float* out_ph) {
    __shared__ int sh_src[256];
    __shared__ float sh_p[256 * KK];
    __shared__ float dloc[KK];
    __shared__ float zsh[256];
    __shared__ float zfin[KK];
    int n = blockIdx.x, tid = threadIdx.x;
    const int Dout = KK * MM;        // 2000
    const int NCH = Dout >> 3;       // 250 chunks
    int start = rs[n], end = rs[n + 1];
    if (tid < KK) dloc[tid] = d[n * KK + tid];
    float zloc = 0.f;
    int hp = tid & (KK - 1);
    float acc[8];
    #pragma unroll
    for (int q = 0; q < 8; q++) acc[q] = 0.f;
    int ch = tid;
    int cb = ch << 3;

    for (int e0 = start; e0 < end; e0 += 256) {
        int cnt = min(256, end - e0);
        if (tid < cnt) sh_src[tid] = csr_src[e0 + tid];
        __syncthreads();
        for (int j = tid; j < cnt * KK; j += 256) {
            int i = j >> 2;
            float p = __expf(lrelu(s[sh_src[i] * KK + hp] + dloc[hp]));
            sh_p[j] = p; zloc += p;
        }
        __syncthreads();
        if (ch < NCH) {
            for (int i = 0; i < cnt; i++) {
                const float* wv = &sh_p[i * KK];
                half8 v = *(const half8*)(xp + (size_t)sh_src[i] * Dout + cb);
                #pragma unroll
                for (int q = 0; q < 8; q++)
                    acc[q] += wv[(cb + q) / MM] * (float)v[q];
            }
        }
        __syncthreads();
    }
    zsh[tid] = zloc;
    __syncthreads();
    if (tid < KK) {
        float zt = 0.f;
        for (int i = tid; i < 256; i += KK) zt += zsh[i];
        zfin[tid] = 1.f / (zt + 1e-16f);
    }
    __syncthreads();
    if (ch < NCH) {
        #pragma unroll
        for (int q = 0; q < 8; q++) {
            int c = cb + q;
            int k = c / MM, m = c - k * MM;
            float v = acc[q] * zfin[k] + bias[c];
            out_ph[((size_t)k * NN + n) * MM + m] = v;
            out_full[(size_t)n * GG + idxm[c]] = v;
        }
    }
}

// ---------- host launcher ----------

extern "C" void kernel_launch(void* const* d_in, const int* in_sizes, int n_in,
                              void* d_out, int out_size, void* d_ws, size_t ws_size,
                              hipStream_t stream) {
    (void)in_sizes; (void)n_in; (void)out_size; (void)ws_size;
    const float* x   = (const float*)d_in[0];
    const int*   ei  = (const int*)d_in[1];
    const float* W1  = (const float*)d_in[2];
    const float* as1 = (const float*)d_in[3];
    const float* ad1 = (const float*)d_in[4];
    const float* b1  = (const float*)d_in[5];
    const float* g1  = (const float*)d_in[6];
    const float* be1 = (const float*)d_in[7];
    const float* W2  = (const float*)d_in[8];
    const float* as2 = (const float*)d_in[9];
    const float* ad2 = (const float*)d_in[10];
    const float* b2  = (const float*)d_in[11];
    const float* g2  = (const float*)d_in[12];
    const float* be2 = (const float*)d_in[13];
    const float* W3  = (const float*)d_in[14];
    const float* as3 = (const float*)d_in[15];
    const float* ad3 = (const float*)d_in[16];
    const float* b3  = (const float*)d_in[17];
    const float* g3  = (const float*)d_in[18];
    const float* be3 = (const float*)d_in[19];
    const float* Wh  = (const float*)d_in[20];
    const float* ash = (const float*)d_in[21];
    const float* adh = (const float*)d_in[22];
    const float* bh  = (const float*)d_in[23];
    const int*   idxm = (const int*)d_in[24];
    float* out = (float*)d_out;

    // workspace carve
    char* w = (char*)d_ws;
    auto carve = [&](size_t bytes) { char* p = w; w += (bytes + 255) & ~(size_t)255; return p; };
    half_t* xp16    = (half_t*)carve((size_t)NN * 3584 * 2);           // GEMM output (fp16)
    half_t* Wt      = (half_t*)carve((size_t)3072 * 3584 * 2);         // transposed fp16 weights (max: W2)
    half_t* agg1    = (half_t*)carve((size_t)NN * HH * D0 * 2);        // L1 aggregated x per head
    float*  sarr    = (float*)carve((size_t)NN * HH * 4);
    float*  darr    = (float*)carve((size_t)NN * HH * 4);
    float*  wa_s    = (float*)carve((size_t)D0 * HH * 4);
    float*  wa_d    = (float*)carve((size_t)D0 * HH * 4);
    int*    csr_src = (int*)carve((size_t)ETOT * 4);
    int*    rowst   = (int*)carve((size_t)(NN + 1) * 4);
    int*    cur     = (int*)carve((size_t)NN * 4);
    // fp16 activations live in d_out (29.4 MB <= 65.5 MB; dead before final writes)
    half_t* Ah = (half_t*)d_out;

    // ---- CSR build ----
    k_zero_i<<<(NN + 255) / 256, 256, 0, stream>>>(cur, NN);
    k_count<<<(ETOT + 255) / 256, 256, 0, stream>>>(ei, cur);
    k_scan<<<1, 1024, 0, stream>>>(cur, rowst, NN);
    k_zero_i<<<(NN + 255) / 256, 256, 0, stream>>>(cur, NN);
    k_fill<<<(ETOT + 255) / 256, 256, 0, stream>>>(ei, rowst, cur, csr_src);

    // ---- x -> fp16 ----
    k_f2h<<<(NN * D0 + 255) / 256, 256, 0, stream>>>(x, Ah, NN * D0);

    // ---- layer 1 (aggregate-x-first restructure) ----
    k_wa<<<D0 * HH, 64, 0, stream>>>(W1, as1, ad1, wa_s, wa_d);
    k_sd_pre<<<NN * HH, 64, 0, stream>>>(x, wa_s, wa_d, sarr, darr);
    k_agg1<<<NN, 256, 0, stream>>>(Ah, sarr, darr, csr_src, rowst, agg1);
    // full transpose of W1 [256][3584] -> Wt[3584][256]; batched per-head GEMM
    k_wt<<<dim3(3584 / 32, D0 / 32, 1), 256, 0, stream>>>(W1, Wt, D0, 3584, 3584, 0, 0);
    k_gemm_mfma<<<dim3(4, NN / BM, HH), 256, 0, stream>>>(
        agg1, Wt, xp16, D0, HH * D0, C1, 3584,
        (long long)D0, (long long)C1 * D0, (long long)C1);
    k_bln<<<NN, 256, 0, stream>>>(xp16, b1, g1, be1, Ah, 3584);

    // ---- layers 2-3 (GEMM-then-gather, fused softmax) ----
    auto gat = [&](const float* W, const float* as_, const float* ad_,
                   const float* bias, const float* gam, const float* bet, int Din, int C) {
        int Dout = HH * C;
        k_wt<<<dim3(Dout / 32, Din / 32, 1), 256, 0, stream>>>(W, Wt, Din, Dout, Dout, 0, 0);
        k_gemm_mfma<<<dim3(Dout / BN, NN / BM, 1), 256, 0, stream>>>(
            Ah, Wt, xp16, Din, Din, Dout, Dout, 0, 0, 0);
        k_sd<<<NN * HH, 64, 0, stream>>>(xp16, as_, ad_, sarr, darr, HH, C);
        k_agg_ln<<<NN, 256, 0, stream>>>(xp16, sarr, darr, csr_src, rowst,
                                         bias, gam, bet, Ah, C);
    };
    gat(W2, as2, ad2, b2, g2, be2, 3584, 384);
    gat(W3, as3, ad3, b3, g3, be3, 3072, 256);

    // ---- head stage ----
    k_wt<<<dim3(512 / 32, 2048 / 32, KK), 256, 0, stream>>>(
        Wh, Wt, 2048, MM, MM, (long long)2048 * MM, (long long)512 * 2048);
    k_gemm_mfma<<<dim3(4, NN / BM, KK), 256, 0, stream>>>(
        Ah, Wt, xp16, 2048, 2048, MM, GG,
        0, (long long)512 * 2048, (long long)MM);
    k_sd<<<NN * KK, 64, 0, stream>>>(xp16, ash, adh, sarr, darr, KK, MM);
    k_zero_f<<<(NN * GG + 255) / 256, 256, 0, stream>>>(out, NN * GG);
    k_agg_head<<<NN, 256, 0, stream>>>(xp16, sarr, darr, csr_src, rowst,
                                       bh, idxm, out, out + (size_t)NN * GG);
}